// Round 4
// baseline (2375.910 us; speedup 1.0000x reference)
//
#include <hip/hip_runtime.h>
#include <hip/hip_bf16.h>

constexpr int D_ = 64;
constexpr int NN = 100000;
constexpr int NE = 1600000;
constexpr int SCAN_B = 1024;
constexpr int NBLK = (NN + SCAN_B - 1) / SCAN_B;  // 98

// ---- count endpoint occurrences (flat edges = 2*NE node ids)
__global__ __launch_bounds__(256) void k_count(const int* __restrict__ ef,
                                               int* __restrict__ cnt, int n) {
  int i = blockIdx.x * 256 + threadIdx.x;
  if (i < n) atomicAdd(cnt + ef[i], 1);
}

// ---- hierarchical scan A: per-block exclusive scan, emit block totals
__global__ __launch_bounds__(1024) void k_scanA(const int* __restrict__ cnt,
                                                int* __restrict__ offs,
                                                int* __restrict__ bsum, int n) {
  __shared__ int sd[1024];
  const int tid = threadIdx.x;
  const int i = blockIdx.x * 1024 + tid;
  int v = (i < n) ? cnt[i] : 0;
  sd[tid] = v;
  __syncthreads();
  for (int off = 1; off < 1024; off <<= 1) {
    int t = (tid >= off) ? sd[tid - off] : 0;
    __syncthreads();
    sd[tid] += t;
    __syncthreads();
  }
  if (i < n) offs[i] = sd[tid] - v;  // exclusive within block
  if (tid == 1023) bsum[blockIdx.x] = sd[1023];
}

// ---- scan B: single block scans the 98 block totals; writes offs[n]=grand total
__global__ __launch_bounds__(128) void k_scanB(int* __restrict__ bsum,
                                               int* __restrict__ offs, int n, int nb) {
  __shared__ int sd[128];
  const int tid = threadIdx.x;
  int v = (tid < nb) ? bsum[tid] : 0;
  sd[tid] = v;
  __syncthreads();
  for (int off = 1; off < 128; off <<= 1) {
    int t = (tid >= off) ? sd[tid - off] : 0;
    __syncthreads();
    sd[tid] += t;
    __syncthreads();
  }
  if (tid < nb) bsum[tid] = sd[tid] - v;  // exclusive block base
  if (tid == 127) offs[n] = sd[127];
}

// ---- scan C: add block base; init fill cursor
__global__ __launch_bounds__(256) void k_scanC(int* __restrict__ offs,
                                               const int* __restrict__ bsum,
                                               int* __restrict__ cur, int n) {
  int i = blockIdx.x * 256 + threadIdx.x;
  if (i < n) {
    int o = offs[i] + bsum[i >> 10];
    offs[i] = o;
    cur[i] = o;
  }
}

// ---- fill neighbor lists via cursor bump
__global__ __launch_bounds__(256) void k_fill(const int* __restrict__ edges,
                                              int* __restrict__ cur,
                                              int* __restrict__ nbr, int ne) {
  int e = blockIdx.x * 256 + threadIdx.x;
  if (e < ne) {
    int s = edges[2 * e];
    int d = edges[2 * e + 1];
    nbr[atomicAdd(cur + d, 1)] = s;
    nbr[atomicAdd(cur + s, 1)] = d;
  }
}

// W staged in LDS transposed+padded: wsT[j*68+k] = W[k*64+j]
// lane j reads ds_read_b128 at j*272+16*k4 -> bank (17j+4k4)%32, conflict-free.
__device__ __forceinline__ void stage_w(const float* __restrict__ W, float* wsT) {
  for (int i = threadIdx.x; i < 4096; i += 256) {
    int k = i >> 6, j = i & 63;
    wsT[j * 68 + k] = W[i];
  }
}

// ---- msg = bf16(h @ W + b)
__global__ __launch_bounds__(256) void k_gemm(const float* __restrict__ h,
                                              const float* __restrict__ W,
                                              const float* __restrict__ b,
                                              __hip_bfloat16* __restrict__ out,
                                              int nrows) {
  __shared__ float wsT[64 * 68];
  stage_w(W, wsT);
  __syncthreads();
  const int lane = threadIdx.x & 63;
  const int wid = (blockIdx.x * 256 + threadIdx.x) >> 6;
  const int nw = (gridDim.x * 256) >> 6;
  const float bias = b[lane];
  const float4* wl = reinterpret_cast<const float4*>(&wsT[lane * 68]);
  for (int r = wid; r < nrows; r += nw) {
    const float4* hr = reinterpret_cast<const float4*>(h + (size_t)r * 64);
    float acc = bias;
#pragma unroll
    for (int k4 = 0; k4 < 16; ++k4) {
      float4 hv = hr[k4];  // wave-uniform -> broadcast
      float4 wv = wl[k4];  // ds_read_b128, conflict-free
      acc = fmaf(hv.x, wv.x, acc);
      acc = fmaf(hv.y, wv.y, acc);
      acc = fmaf(hv.z, wv.z, acc);
      acc = fmaf(hv.w, wv.w, acc);
    }
    out[(size_t)r * 64 + lane] = __float2bfloat16(acc);
  }
}

// ---- out = h @ W0 + b0 + gather(msg)/deg ; optional fused LayerNorm + ReLU
template <bool LN>
__global__ __launch_bounds__(256, 8) void k_conv_out(
    const float* __restrict__ h, const float* __restrict__ W,
    const float* __restrict__ b, const __hip_bfloat16* __restrict__ msg,
    const int* __restrict__ offs, const int* __restrict__ nbr,
    const float* __restrict__ gamma, const float* __restrict__ beta,
    float* __restrict__ out, int nrows) {
  __shared__ float wsT[64 * 68];
  stage_w(W, wsT);
  __syncthreads();
  const int lane = threadIdx.x & 63;
  const int wid = (blockIdx.x * 256 + threadIdx.x) >> 6;
  const int nw = (gridDim.x * 256) >> 6;
  const float bias = b[lane];
  float gm = 1.0f, bt = 0.0f;
  if (LN) { gm = gamma[lane]; bt = beta[lane]; }
  const float4* wl = reinterpret_cast<const float4*>(&wsT[lane * 68]);
  for (int r = wid; r < nrows; r += nw) {
    const float4* hr = reinterpret_cast<const float4*>(h + (size_t)r * 64);
    float acc = bias;
#pragma unroll
    for (int k4 = 0; k4 < 16; ++k4) {
      float4 hv = hr[k4];
      float4 wv = wl[k4];
      acc = fmaf(hv.x, wv.x, acc);
      acc = fmaf(hv.y, wv.y, acc);
      acc = fmaf(hv.z, wv.z, acc);
      acc = fmaf(hv.w, wv.w, acc);
    }
    // gather: 16 independent loads in flight per batch
    const int n0 = offs[r], n1 = offs[r + 1];
    float ag = 0.0f;
    int j = n0;
    for (; j + 16 <= n1; j += 16) {
      int idx[16];
#pragma unroll
      for (int u = 0; u < 16; ++u) idx[u] = nbr[j + u];
      float m[16];
#pragma unroll
      for (int u = 0; u < 16; ++u)
        m[u] = __bfloat162float(msg[(size_t)idx[u] * 64 + lane]);
      float s0 = ((m[0] + m[1]) + (m[2] + m[3])) + ((m[4] + m[5]) + (m[6] + m[7]));
      float s1 = ((m[8] + m[9]) + (m[10] + m[11])) + ((m[12] + m[13]) + (m[14] + m[15]));
      ag += s0 + s1;
    }
    for (; j + 4 <= n1; j += 4) {
      int idx[4];
#pragma unroll
      for (int u = 0; u < 4; ++u) idx[u] = nbr[j + u];
      float m[4];
#pragma unroll
      for (int u = 0; u < 4; ++u)
        m[u] = __bfloat162float(msg[(size_t)idx[u] * 64 + lane]);
      ag += (m[0] + m[1]) + (m[2] + m[3]);
    }
    for (; j < n1; ++j) ag += __bfloat162float(msg[(size_t)nbr[j] * 64 + lane]);
    const float rdeg = 1.0f / fmaxf((float)(n1 - n0), 1.0f);
    float val = fmaf(ag, rdeg, acc);
    if (LN) {
      float s = val;
#pragma unroll
      for (int off = 32; off > 0; off >>= 1) s += __shfl_xor(s, off, 64);
      const float mu = s * (1.0f / 64.0f);
      const float dv = val - mu;
      float v2 = dv * dv;
#pragma unroll
      for (int off = 32; off > 0; off >>= 1) v2 += __shfl_xor(v2, off, 64);
      const float var = v2 * (1.0f / 64.0f);
      val = fmaxf(fmaf(dv * rsqrtf(var + 1e-5f), gm, bt), 0.0f);
    }
    out[(size_t)r * 64 + lane] = val;
  }
}

extern "C" void kernel_launch(void* const* d_in, const int* in_sizes, int n_in,
                              void* d_out, int out_size, void* d_ws, size_t ws_size,
                              hipStream_t stream) {
  const float* vert = (const float*)d_in[0];
  const int* edges = (const int*)d_in[1];
  const float* W0 = (const float*)d_in[2];
  const float* b0 = (const float*)d_in[3];
  const float* W1 = (const float*)d_in[4];
  const float* b1 = (const float*)d_in[5];
  const float* lng = (const float*)d_in[6];
  const float* lnb = (const float*)d_in[7];
  float* out = (float*)d_out;

  const size_t HB = (size_t)NN * D_ * sizeof(float);  // 25.6 MB
  float* hbuf = (float*)d_ws;
  int* nbr = (int*)((char*)d_ws + HB);                        // 2*NE ints
  int* offs = (int*)((char*)d_ws + HB + (size_t)2 * NE * 4);  // NN+1
  int* cur = offs + (NN + 1);                                 // NN
  int* cnt = cur + NN;                                        // NN
  int* bsum = cnt + NN;                                       // NBLK
  __hip_bfloat16* msg = (__hip_bfloat16*)out;                 // 12.8 MB in d_out

  // ---- CSR build
  hipMemsetAsync(cnt, 0, NN * sizeof(int), stream);
  k_count<<<(2 * NE + 255) / 256, 256, 0, stream>>>(edges, cnt, 2 * NE);
  k_scanA<<<NBLK, 1024, 0, stream>>>(cnt, offs, bsum, NN);
  k_scanB<<<1, 128, 0, stream>>>(bsum, offs, NN, NBLK);
  k_scanC<<<(NN + 255) / 256, 256, 0, stream>>>(offs, bsum, cur, NN);
  k_fill<<<(NE + 255) / 256, 256, 0, stream>>>(edges, cur, nbr, NE);

  const int GB = 2048;

  // layer 0
  k_gemm<<<GB, 256, 0, stream>>>(vert, W1, b1, msg, NN);
  k_conv_out<true><<<GB, 256, 0, stream>>>(vert, W0, b0, msg, offs, nbr,
                                           lng, lnb, hbuf, NN);
  // layer 1 (in-place h: each wave reads only its own row before writing)
  k_gemm<<<GB, 256, 0, stream>>>(hbuf, W1 + 4096, b1 + 64, msg, NN);
  k_conv_out<true><<<GB, 256, 0, stream>>>(hbuf, W0 + 4096, b0 + 64, msg, offs, nbr,
                                           lng + 64, lnb + 64, hbuf, NN);
  // layer 2: msg aliases d_out -> write to hbuf, then d2d copy
  k_gemm<<<GB, 256, 0, stream>>>(hbuf, W1 + 8192, b1 + 128, msg, NN);
  k_conv_out<false><<<GB, 256, 0, stream>>>(hbuf, W0 + 8192, b0 + 128, msg, offs, nbr,
                                            nullptr, nullptr, hbuf, NN);
  hipMemcpyAsync(out, hbuf, HB, hipMemcpyDeviceToDevice, stream);
}

// Round 5
// 1107.667 us; speedup vs baseline: 2.1450x; 2.1450x over previous
//
#include <hip/hip_runtime.h>
#include <hip/hip_bf16.h>

constexpr int D_ = 64;
constexpr int NN = 100000;
constexpr int NE = 1600000;
constexpr int NBLK = (NN + 1023) / 1024;  // 98

// ---- count endpoint occurrences (flat edges = 2*NE node ids)
__global__ __launch_bounds__(256) void k_count(const int* __restrict__ ef,
                                               int* __restrict__ cnt, int n) {
  int i = blockIdx.x * 256 + threadIdx.x;
  if (i < n) atomicAdd(cnt + ef[i], 1);
}

// ---- hierarchical scan A: per-block exclusive scan, emit block totals
__global__ __launch_bounds__(1024) void k_scanA(const int* __restrict__ cnt,
                                                int* __restrict__ offs,
                                                int* __restrict__ bsum, int n) {
  __shared__ int sd[1024];
  const int tid = threadIdx.x;
  const int i = blockIdx.x * 1024 + tid;
  int v = (i < n) ? cnt[i] : 0;
  sd[tid] = v;
  __syncthreads();
  for (int off = 1; off < 1024; off <<= 1) {
    int t = (tid >= off) ? sd[tid - off] : 0;
    __syncthreads();
    sd[tid] += t;
    __syncthreads();
  }
  if (i < n) offs[i] = sd[tid] - v;
  if (tid == 1023) bsum[blockIdx.x] = sd[1023];
}

// ---- scan B: single block scans block totals; writes offs[n]=grand total
__global__ __launch_bounds__(128) void k_scanB(int* __restrict__ bsum,
                                               int* __restrict__ offs, int n, int nb) {
  __shared__ int sd[128];
  const int tid = threadIdx.x;
  int v = (tid < nb) ? bsum[tid] : 0;
  sd[tid] = v;
  __syncthreads();
  for (int off = 1; off < 128; off <<= 1) {
    int t = (tid >= off) ? sd[tid - off] : 0;
    __syncthreads();
    sd[tid] += t;
    __syncthreads();
  }
  if (tid < nb) bsum[tid] = sd[tid] - v;
  if (tid == 127) offs[n] = sd[127];
}

// ---- scan C: add block base; init fill cursor (cur aliases dead cnt buffer)
__global__ __launch_bounds__(256) void k_scanC(int* __restrict__ offs,
                                               const int* __restrict__ bsum,
                                               int* __restrict__ cur, int n) {
  int i = blockIdx.x * 256 + threadIdx.x;
  if (i < n) {
    int o = offs[i] + bsum[i >> 10];
    offs[i] = o;
    cur[i] = o;
  }
}

// ---- fill neighbor lists via cursor bump
__global__ __launch_bounds__(256) void k_fill(const int* __restrict__ edges,
                                              int* __restrict__ cur,
                                              int* __restrict__ nbr, int ne) {
  int e = blockIdx.x * 256 + threadIdx.x;
  if (e < ne) {
    int s = edges[2 * e];
    int d = edges[2 * e + 1];
    nbr[atomicAdd(cur + d, 1)] = s;
    nbr[atomicAdd(cur + s, 1)] = d;
  }
}

// W staged transposed+padded: wT[j*68+k] = W[k*64+j]; lane j reads float4 runs.
__device__ __forceinline__ void stage_w(const float* __restrict__ W, float* wT) {
  for (int i = threadIdx.x; i < 4096; i += 256) {
    int k = i >> 6, j = i & 63;
    wT[j * 68 + k] = W[i];
  }
}

// ---- one streaming pass: base = h@W0+b0 (f32), msg = bf16(h@W1+b1)
__global__ __launch_bounds__(256) void k_gemm2(
    const float* __restrict__ h, const float* __restrict__ W0,
    const float* __restrict__ b0, const float* __restrict__ W1,
    const float* __restrict__ b1, float* __restrict__ base,
    __hip_bfloat16* __restrict__ msg, int nrows) {
  __shared__ float w0T[64 * 68];
  __shared__ float w1T[64 * 68];
  stage_w(W0, w0T);
  stage_w(W1, w1T);
  __syncthreads();
  const int lane = threadIdx.x & 63;
  const int wid = (blockIdx.x * 256 + threadIdx.x) >> 6;
  const int nw = (gridDim.x * 256) >> 6;
  const float bv0 = b0[lane], bv1 = b1[lane];
  const float4* wl0 = reinterpret_cast<const float4*>(&w0T[lane * 68]);
  const float4* wl1 = reinterpret_cast<const float4*>(&w1T[lane * 68]);
  for (int r = wid; r < nrows; r += nw) {
    const float4* hr = reinterpret_cast<const float4*>(h + (size_t)r * 64);
    float a0 = bv0, a1 = bv1;
#pragma unroll
    for (int k4 = 0; k4 < 16; ++k4) {
      float4 hv = hr[k4];  // wave-uniform -> broadcast
      float4 v0 = wl0[k4];
      float4 v1 = wl1[k4];
      a0 = fmaf(hv.x, v0.x, a0); a1 = fmaf(hv.x, v1.x, a1);
      a0 = fmaf(hv.y, v0.y, a0); a1 = fmaf(hv.y, v1.y, a1);
      a0 = fmaf(hv.z, v0.z, a0); a1 = fmaf(hv.z, v1.z, a1);
      a0 = fmaf(hv.w, v0.w, a0); a1 = fmaf(hv.w, v1.w, a1);
    }
    base[(size_t)r * 64 + lane] = a0;
    msg[(size_t)r * 64 + lane] = __float2bfloat16(a1);
  }
}

// ---- gather-only: out = base + gather(msg)/deg ; optional LN+ReLU.
// No W, no LDS -> registers free for a true 16-deep in-flight batch.
template <bool LN>
__global__ __launch_bounds__(256) void k_agg(
    const float* __restrict__ base, const __hip_bfloat16* __restrict__ msg,
    const int* __restrict__ offs, const int* __restrict__ nbr,
    const float* __restrict__ gamma, const float* __restrict__ beta,
    float* __restrict__ out, int nrows) {
  const int lane = threadIdx.x & 63;
  const int wid = (blockIdx.x * 256 + threadIdx.x) >> 6;
  const int nw = (gridDim.x * 256) >> 6;
  float gm = 1.0f, bt = 0.0f;
  if (LN) { gm = gamma[lane]; bt = beta[lane]; }
  for (int r = wid; r < nrows; r += nw) {
    const int n0 = offs[r], n1 = offs[r + 1];
    const float bval = base[(size_t)r * 64 + lane];  // issued early, in flight
    float ag = 0.0f;
    int j = n0;
    for (; j + 16 <= n1; j += 16) {
      int idx[16];
#pragma unroll
      for (int u = 0; u < 16; ++u) idx[u] = nbr[j + u];
      float m[16];
#pragma unroll
      for (int u = 0; u < 16; ++u)
        m[u] = __bfloat162float(msg[(idx[u] << 6) + lane]);  // saddr+voffset form
      float s0 = ((m[0] + m[1]) + (m[2] + m[3])) + ((m[4] + m[5]) + (m[6] + m[7]));
      float s1 = ((m[8] + m[9]) + (m[10] + m[11])) + ((m[12] + m[13]) + (m[14] + m[15]));
      ag += s0 + s1;
    }
    for (; j + 4 <= n1; j += 4) {
      int idx[4];
#pragma unroll
      for (int u = 0; u < 4; ++u) idx[u] = nbr[j + u];
      float m[4];
#pragma unroll
      for (int u = 0; u < 4; ++u)
        m[u] = __bfloat162float(msg[(idx[u] << 6) + lane]);
      ag += (m[0] + m[1]) + (m[2] + m[3]);
    }
    for (; j < n1; ++j) ag += __bfloat162float(msg[((int)nbr[j] << 6) + lane]);
    const float rdeg = 1.0f / fmaxf((float)(n1 - n0), 1.0f);
    float val = fmaf(ag, rdeg, bval);
    if (LN) {
      float s = val;
#pragma unroll
      for (int off = 32; off > 0; off >>= 1) s += __shfl_xor(s, off, 64);
      const float mu = s * (1.0f / 64.0f);
      const float dv = val - mu;
      float v2 = dv * dv;
#pragma unroll
      for (int off = 32; off > 0; off >>= 1) v2 += __shfl_xor(v2, off, 64);
      const float var = v2 * (1.0f / 64.0f);
      val = fmaxf(fmaf(dv * rsqrtf(var + 1e-5f), gm, bt), 0.0f);
    }
    out[(size_t)r * 64 + lane] = val;
  }
}

extern "C" void kernel_launch(void* const* d_in, const int* in_sizes, int n_in,
                              void* d_out, int out_size, void* d_ws, size_t ws_size,
                              hipStream_t stream) {
  const float* vert = (const float*)d_in[0];
  const int* edges = (const int*)d_in[1];
  const float* W0 = (const float*)d_in[2];
  const float* b0 = (const float*)d_in[3];
  const float* W1 = (const float*)d_in[4];
  const float* b1 = (const float*)d_in[5];
  const float* lng = (const float*)d_in[6];
  const float* lnb = (const float*)d_in[7];
  float* base = (float*)d_out;  // base buffer lives in d_out all layers

  // ws layout (51.6 MB): hbuf | nbr | msg (aliases cnt+bsum during CSR build) | offs
  const size_t HB = (size_t)NN * D_ * sizeof(float);  // 25.6 MB
  float* hbuf = (float*)d_ws;
  int* nbr = (int*)((char*)d_ws + HB);                              // 12.8 MB
  __hip_bfloat16* msg = (__hip_bfloat16*)((char*)d_ws + HB + (size_t)2 * NE * 4);
  int* cnt = (int*)msg;                                             // CSR-build only
  int* bsum = cnt + NN;
  int* offs = (int*)((char*)d_ws + HB + (size_t)2 * NE * 4 + HB / 2);
  int* cur = cnt;  // cnt dead after scanA

  // ---- CSR build
  hipMemsetAsync(cnt, 0, NN * sizeof(int), stream);
  k_count<<<(2 * NE + 255) / 256, 256, 0, stream>>>(edges, cnt, 2 * NE);
  k_scanA<<<NBLK, 1024, 0, stream>>>(cnt, offs, bsum, NN);
  k_scanB<<<1, 128, 0, stream>>>(bsum, offs, NN, NBLK);
  k_scanC<<<(NN + 255) / 256, 256, 0, stream>>>(offs, bsum, cur, NN);
  k_fill<<<(NE + 255) / 256, 256, 0, stream>>>(edges, cur, nbr, NE);

  const int GB = 2048;

  for (int l = 0; l < 3; ++l) {
    const float* hcur = (l == 0) ? vert : hbuf;
    k_gemm2<<<GB, 256, 0, stream>>>(hcur, W0 + l * 4096, b0 + l * 64,
                                    W1 + l * 4096, b1 + l * 64, base, msg, NN);
    if (l < 2) {
      k_agg<true><<<GB, 256, 0, stream>>>(base, msg, offs, nbr,
                                          lng + l * 64, lnb + l * 64, hbuf, NN);
    } else {
      // in-place: each thread reads base[r*64+lane] then writes same address
      k_agg<false><<<GB, 256, 0, stream>>>(base, msg, offs, nbr,
                                           nullptr, nullptr, base, NN);
    }
  }
}

// Round 6
// 1081.622 us; speedup vs baseline: 2.1966x; 1.0241x over previous
//
#include <hip/hip_runtime.h>
#include <hip/hip_bf16.h>

constexpr int D_ = 64;
constexpr int NN = 100000;
constexpr int NE = 1600000;
constexpr int NBLK = (NN + 1023) / 1024;  // 98

__device__ __forceinline__ float bflo(unsigned v) { return __uint_as_float(v << 16); }
__device__ __forceinline__ float bfhi(unsigned v) { return __uint_as_float(v & 0xffff0000u); }

// ---- count endpoint occurrences; 8 endpoints/thread -> 8 atomics in flight
__global__ __launch_bounds__(256) void k_count(const int* __restrict__ ef,
                                               int* __restrict__ cnt, int n) {
  int t = blockIdx.x * 256 + threadIdx.x;
  int i0 = t * 8;
  if (i0 + 8 <= n) {
    const int4* p = reinterpret_cast<const int4*>(ef + i0);
    int4 a = p[0], b = p[1];
    atomicAdd(cnt + a.x, 1); atomicAdd(cnt + a.y, 1);
    atomicAdd(cnt + a.z, 1); atomicAdd(cnt + a.w, 1);
    atomicAdd(cnt + b.x, 1); atomicAdd(cnt + b.y, 1);
    atomicAdd(cnt + b.z, 1); atomicAdd(cnt + b.w, 1);
  } else {
    for (int i = i0; i < n; ++i) atomicAdd(cnt + ef[i], 1);
  }
}

// ---- hierarchical scan A: per-block exclusive scan, emit block totals
__global__ __launch_bounds__(1024) void k_scanA(const int* __restrict__ cnt,
                                                int* __restrict__ offs,
                                                int* __restrict__ bsum, int n) {
  __shared__ int sd[1024];
  const int tid = threadIdx.x;
  const int i = blockIdx.x * 1024 + tid;
  int v = (i < n) ? cnt[i] : 0;
  sd[tid] = v;
  __syncthreads();
  for (int off = 1; off < 1024; off <<= 1) {
    int t = (tid >= off) ? sd[tid - off] : 0;
    __syncthreads();
    sd[tid] += t;
    __syncthreads();
  }
  if (i < n) offs[i] = sd[tid] - v;
  if (tid == 1023) bsum[blockIdx.x] = sd[1023];
}

// ---- scan B: single block scans block totals; writes offs[n]=grand total
__global__ __launch_bounds__(128) void k_scanB(int* __restrict__ bsum,
                                               int* __restrict__ offs, int n, int nb) {
  __shared__ int sd[128];
  const int tid = threadIdx.x;
  int v = (tid < nb) ? bsum[tid] : 0;
  sd[tid] = v;
  __syncthreads();
  for (int off = 1; off < 128; off <<= 1) {
    int t = (tid >= off) ? sd[tid - off] : 0;
    __syncthreads();
    sd[tid] += t;
    __syncthreads();
  }
  if (tid < nb) bsum[tid] = sd[tid] - v;
  if (tid == 127) offs[n] = sd[127];
}

// ---- scan C: add block base; init fill cursor
__global__ __launch_bounds__(256) void k_scanC(int* __restrict__ offs,
                                               const int* __restrict__ bsum,
                                               int* __restrict__ cur, int n) {
  int i = blockIdx.x * 256 + threadIdx.x;
  if (i < n) {
    int o = offs[i] + bsum[i >> 10];
    offs[i] = o;
    cur[i] = o;
  }
}

// ---- fill: 4 edges/thread -> 8 atomic chains in flight, then 8 stores
__global__ __launch_bounds__(256) void k_fill(const int* __restrict__ edges,
                                              int* __restrict__ cur,
                                              int* __restrict__ nbr, int ne) {
  int t = blockIdx.x * 256 + threadIdx.x;
  int e0 = t * 4;
  if (e0 + 4 <= ne) {
    const int4* ep = reinterpret_cast<const int4*>(edges + 2 * e0);
    int4 e01 = ep[0], e23 = ep[1];  // (s0,d0,s1,d1), (s2,d2,s3,d3)
    int p0 = atomicAdd(cur + e01.y, 1);
    int p1 = atomicAdd(cur + e01.x, 1);
    int p2 = atomicAdd(cur + e01.w, 1);
    int p3 = atomicAdd(cur + e01.z, 1);
    int p4 = atomicAdd(cur + e23.y, 1);
    int p5 = atomicAdd(cur + e23.x, 1);
    int p6 = atomicAdd(cur + e23.w, 1);
    int p7 = atomicAdd(cur + e23.z, 1);
    nbr[p0] = e01.x; nbr[p1] = e01.y;
    nbr[p2] = e01.z; nbr[p3] = e01.w;
    nbr[p4] = e23.x; nbr[p5] = e23.y;
    nbr[p6] = e23.z; nbr[p7] = e23.w;
  } else {
    for (int e = e0; e < ne; ++e) {
      int s = edges[2 * e], d = edges[2 * e + 1];
      nbr[atomicAdd(cur + d, 1)] = s;
      nbr[atomicAdd(cur + s, 1)] = d;
    }
  }
}

// W staged transposed+padded: wT[j*68+k] = W[k*64+j]
__device__ __forceinline__ void stage_w(const float* __restrict__ W, float* wT) {
  for (int i = threadIdx.x; i < 4096; i += 256) {
    int k = i >> 6, j = i & 63;
    wT[j * 68 + k] = W[i];
  }
}

// ---- one streaming pass: base = h@W0+b0 (f32), msg = bf16(h@W1+b1)
__global__ __launch_bounds__(256) void k_gemm2(
    const float* __restrict__ h, const float* __restrict__ W0,
    const float* __restrict__ b0, const float* __restrict__ W1,
    const float* __restrict__ b1, float* __restrict__ base,
    __hip_bfloat16* __restrict__ msg, int nrows) {
  __shared__ float w0T[64 * 68];
  __shared__ float w1T[64 * 68];
  stage_w(W0, w0T);
  stage_w(W1, w1T);
  __syncthreads();
  const int lane = threadIdx.x & 63;
  const int wid = (blockIdx.x * 256 + threadIdx.x) >> 6;
  const int nw = (gridDim.x * 256) >> 6;
  const float bv0 = b0[lane], bv1 = b1[lane];
  const float4* wl0 = reinterpret_cast<const float4*>(&w0T[lane * 68]);
  const float4* wl1 = reinterpret_cast<const float4*>(&w1T[lane * 68]);
  for (int r = wid; r < nrows; r += nw) {
    const float4* hr = reinterpret_cast<const float4*>(h + (size_t)r * 64);
    float a0 = bv0, a1 = bv1;
#pragma unroll
    for (int k4 = 0; k4 < 16; ++k4) {
      float4 hv = hr[k4];
      float4 v0 = wl0[k4];
      float4 v1 = wl1[k4];
      a0 = fmaf(hv.x, v0.x, a0); a1 = fmaf(hv.x, v1.x, a1);
      a0 = fmaf(hv.y, v0.y, a0); a1 = fmaf(hv.y, v1.y, a1);
      a0 = fmaf(hv.z, v0.z, a0); a1 = fmaf(hv.z, v1.z, a1);
      a0 = fmaf(hv.w, v0.w, a0); a1 = fmaf(hv.w, v1.w, a1);
    }
    base[(size_t)r * 64 + lane] = a0;
    msg[(size_t)r * 64 + lane] = __float2bfloat16(a1);
  }
}

// ---- gather: half-wave pair loads (2 neighbor rows per instruction)
template <bool LN>
__global__ __launch_bounds__(256) void k_agg(
    const float* __restrict__ base, const __hip_bfloat16* __restrict__ msg,
    const int* __restrict__ offs, const int* __restrict__ nbr,
    const float* __restrict__ gamma, const float* __restrict__ beta,
    float* __restrict__ out, int nrows) {
  const int lane = threadIdx.x & 63;
  const int half = lane >> 5;   // which neighbor of each pair
  const int c = lane & 31;      // column-pair index (cols 2c, 2c+1)
  const int wid = (blockIdx.x * 256 + threadIdx.x) >> 6;
  const int nw = (gridDim.x * 256) >> 6;
  float gm = 1.0f, bt = 0.0f;
  if (LN) { gm = gamma[lane]; bt = beta[lane]; }
  const unsigned* msg32 = reinterpret_cast<const unsigned*>(msg);  // row = 32 dwords
  for (int r = wid; r < nrows; r += nw) {
    const int n0 = offs[r], n1 = offs[r + 1];
    const float bval = base[(size_t)r * 64 + lane];  // in flight during gather
    float agx = 0.0f, agy = 0.0f;
    int j = n0;
    for (; j + 32 <= n1; j += 32) {  // 16 pair-loads = 32 rows in flight
      int idx[16];
#pragma unroll
      for (int u = 0; u < 16; ++u) idx[u] = nbr[j + 2 * u + half];
      unsigned mv[16];
#pragma unroll
      for (int u = 0; u < 16; ++u) mv[u] = msg32[(idx[u] << 5) + c];
#pragma unroll
      for (int u = 0; u < 16; ++u) { agx += bflo(mv[u]); agy += bfhi(mv[u]); }
    }
    for (; j + 8 <= n1; j += 8) {
      int idx[4];
#pragma unroll
      for (int u = 0; u < 4; ++u) idx[u] = nbr[j + 2 * u + half];
      unsigned mv[4];
#pragma unroll
      for (int u = 0; u < 4; ++u) mv[u] = msg32[(idx[u] << 5) + c];
#pragma unroll
      for (int u = 0; u < 4; ++u) { agx += bflo(mv[u]); agy += bfhi(mv[u]); }
    }
    for (; j + 2 <= n1; j += 2) {
      unsigned mv = msg32[(nbr[j + half] << 5) + c];
      agx += bflo(mv); agy += bfhi(mv);
    }
    // combine halves, then redistribute pair-sums to per-column lanes
    agx += __shfl_xor(agx, 32, 64);
    agy += __shfl_xor(agy, 32, 64);
    float tx = __shfl(agx, lane >> 1, 64);
    float ty = __shfl(agy, lane >> 1, 64);
    float ag = (lane & 1) ? ty : tx;
    for (; j < n1; ++j)  // at most 1 leftover neighbor
      ag += __bfloat162float(msg[((int)nbr[j] << 6) + lane]);
    const float rdeg = 1.0f / fmaxf((float)(n1 - n0), 1.0f);
    float val = fmaf(ag, rdeg, bval);
    if (LN) {
      float s = val;
#pragma unroll
      for (int off = 32; off > 0; off >>= 1) s += __shfl_xor(s, off, 64);
      const float mu = s * (1.0f / 64.0f);
      const float dv = val - mu;
      float v2 = dv * dv;
#pragma unroll
      for (int off = 32; off > 0; off >>= 1) v2 += __shfl_xor(v2, off, 64);
      const float var = v2 * (1.0f / 64.0f);
      val = fmaxf(fmaf(dv * rsqrtf(var + 1e-5f), gm, bt), 0.0f);
    }
    out[(size_t)r * 64 + lane] = val;
  }
}

extern "C" void kernel_launch(void* const* d_in, const int* in_sizes, int n_in,
                              void* d_out, int out_size, void* d_ws, size_t ws_size,
                              hipStream_t stream) {
  const float* vert = (const float*)d_in[0];
  const int* edges = (const int*)d_in[1];
  const float* W0 = (const float*)d_in[2];
  const float* b0 = (const float*)d_in[3];
  const float* W1 = (const float*)d_in[4];
  const float* b1 = (const float*)d_in[5];
  const float* lng = (const float*)d_in[6];
  const float* lnb = (const float*)d_in[7];
  float* base = (float*)d_out;  // base buffer lives in d_out all layers

  const size_t HB = (size_t)NN * D_ * sizeof(float);  // 25.6 MB
  float* hbuf = (float*)d_ws;
  int* nbr = (int*)((char*)d_ws + HB);                              // 12.8 MB
  __hip_bfloat16* msg = (__hip_bfloat16*)((char*)d_ws + HB + (size_t)2 * NE * 4);
  int* cnt = (int*)msg;  // CSR-build only (dead before msg is written)
  int* bsum = cnt + NN;
  int* offs = (int*)((char*)d_ws + HB + (size_t)2 * NE * 4 + HB / 2);
  int* cur = cnt;  // cnt dead after scanA

  // ---- CSR build
  hipMemsetAsync(cnt, 0, NN * sizeof(int), stream);
  k_count<<<(2 * NE / 8 + 255) / 256, 256, 0, stream>>>(edges, cnt, 2 * NE);
  k_scanA<<<NBLK, 1024, 0, stream>>>(cnt, offs, bsum, NN);
  k_scanB<<<1, 128, 0, stream>>>(bsum, offs, NN, NBLK);
  k_scanC<<<(NN + 255) / 256, 256, 0, stream>>>(offs, bsum, cur, NN);
  k_fill<<<(NE / 4 + 255) / 256, 256, 0, stream>>>(edges, cur, nbr, NE);

  const int GB = 2048;

  for (int l = 0; l < 3; ++l) {
    const float* hcur = (l == 0) ? vert : hbuf;
    k_gemm2<<<GB, 256, 0, stream>>>(hcur, W0 + l * 4096, b0 + l * 64,
                                    W1 + l * 4096, b1 + l * 64, base, msg, NN);
    if (l < 2) {
      k_agg<true><<<GB, 256, 0, stream>>>(base, msg, offs, nbr,
                                          lng + l * 64, lnb + l * 64, hbuf, NN);
    } else {
      k_agg<false><<<GB, 256, 0, stream>>>(base, msg, offs, nbr,
                                           nullptr, nullptr, base, NN);
    }
  }
}